// Round 1
// baseline (3582.623 us; speedup 1.0000x reference)
//
#include <hip/hip_runtime.h>
#include <cstddef>

namespace {

constexpr int NB = 256;  // batch
constexpr int NT = 512;  // time
constexpr int NF = 64;   // feature
constexpr int NH = 128;  // hidden
constexpr int NG = 512;  // 4*NH gates

__device__ __forceinline__ float sigm(float x) { return 1.0f / (1.0f + __expf(-x)); }
__device__ __forceinline__ float tanh_(float x) { return 2.0f / (1.0f + __expf(-2.0f * x)) - 1.0f; }
__device__ __forceinline__ float dot4(float4 w, float4 v, float acc) {
  return fmaf(w.x, v.x, fmaf(w.y, v.y, fmaf(w.z, v.z, fmaf(w.w, v.w, acc))));
}

// MODE: 0 = seq-in -> seq-out            (enc layer 0)
//       1 = seq-in -> hT-out             (enc layer 1)
//       2 = const-in (hT) -> seq-out     (dec layer 0; input constant over t)
//       3 = seq-in -> fused projection   (dec layer 1 + W_out)
// One block per batch element, 512 threads (8 waves).
// Gate order (PyTorch/reference): i = [0,128), f = [128,256), g = [256,384), o = [384,512).
template <int I, int MODE>
__global__ __launch_bounds__(512, 2) void lstm_kernel(
    const float* __restrict__ in_seq,  // [NB,NT,I]   (modes 0,1,3)
    const float* __restrict__ hT_in,   // [NB,NH]     (mode 2)
    const float* __restrict__ Wih,     // [NG,I]
    const float* __restrict__ Whh,     // [NG,NH]
    const float* __restrict__ bih,     // [NG]
    const float* __restrict__ bhh,     // [NG]
    const float* __restrict__ Wout,    // [NF,NH]     (mode 3)
    const float* __restrict__ bout,    // [NF]        (mode 3)
    float* __restrict__ seq_out,       // [NB,NT,NH]  (modes 0,2)
    float* __restrict__ hT_out,        // [NB,NH]     (mode 1)
    float* __restrict__ proj_out)      // [NB,NT,NF]  (mode 3)
{
  constexpr int TTB = (MODE == 2) ? 1 : 16;   // timesteps per chunk
  constexpr int NCHUNK = NT / TTB;

  const int b = blockIdx.x;
  const int tid = threadIdx.x;
  const int j = tid >> 2;   // hidden unit [0,128)
  const int kq = tid & 3;   // k-quarter  [0,4)

  // h double-buffer: [parity][k-quarter][36] -- 36-float padded rows so the 4
  // quarter base addresses land on distinct banks (kq*36 mod 32 = 4*kq).
  __shared__ __align__(16) float hbuf[2][4][36];
  __shared__ __align__(16) float xg_all[TTB * NG];                    // per-chunk input contributions
  __shared__ __align__(16) float in_lds[(MODE == 2) ? NH : (TTB * I)];
  __shared__ float psum[128];                                         // mode-3 projection partials

  // W_hh fragment in registers: 4 gates {j, j+128, j+256, j+384}, k in [kq*32, kq*32+32).
  float4 wh[4][8];
#pragma unroll
  for (int gi = 0; gi < 4; ++gi) {
    const float4* p = reinterpret_cast<const float4*>(Whh + (size_t)(gi * NH + j) * NH + kq * 32);
#pragma unroll
    for (int r = 0; r < 8; ++r) wh[gi][r] = p[r];
  }

  const float bias_g = bih[tid] + bhh[tid];  // thread==gate mapping for the input-GEMM phase
  float bout_reg = 0.0f;
  if (MODE == 3 && tid < NF) bout_reg = bout[tid];

  if (tid < NH) hbuf[0][tid >> 5][tid & 31] = 0.0f;  // h0 = 0 (read at t=0, parity 0)
  float c = 0.0f;                                    // c0 = 0 (replicated across the 4 kq lanes)

  if (MODE == 2) {
    // Constant input contribution: xg_c[g] = bias + W_ih[g,:] . hT[b,:]
    if (tid < NH) in_lds[tid] = hT_in[(size_t)b * NH + tid];
    __syncthreads();
    const float4* wr = reinterpret_cast<const float4*>(Wih + (size_t)tid * NH);
    const float4* hv = reinterpret_cast<const float4*>(in_lds);
    float a0 = bias_g, a1 = 0.f, a2 = 0.f, a3 = 0.f;
#pragma unroll
    for (int k4 = 0; k4 < NH / 4; k4 += 4) {
      a0 = dot4(wr[k4 + 0], hv[k4 + 0], a0);
      a1 = dot4(wr[k4 + 1], hv[k4 + 1], a1);
      a2 = dot4(wr[k4 + 2], hv[k4 + 2], a2);
      a3 = dot4(wr[k4 + 3], hv[k4 + 3], a3);
    }
    xg_all[tid] = (a0 + a1) + (a2 + a3);
    __syncthreads();
  }

  for (int chunk = 0; chunk < NCHUNK; ++chunk) {
    if (MODE != 2) {
      // ---- stage input chunk [TTB x I] into LDS (coalesced float4) ----
      const float4* src4 =
          reinterpret_cast<const float4*>(in_seq + ((size_t)b * NT + (size_t)chunk * TTB) * I);
      float4* dst4 = reinterpret_cast<float4*>(in_lds);
      for (int i = tid; i < TTB * I / 4; i += 512) dst4[i] = src4[i];
      __syncthreads();

      // ---- input GEMM for this chunk: thread == gate, W_ih row streamed from L2 ----
      float xg[TTB];
#pragma unroll
      for (int tt = 0; tt < TTB; ++tt) xg[tt] = bias_g;
      const float4* wr = reinterpret_cast<const float4*>(Wih + (size_t)tid * I);
      const float4* iv = reinterpret_cast<const float4*>(in_lds);
#pragma unroll 4
      for (int k4 = 0; k4 < I / 4; ++k4) {
        const float4 w4 = wr[k4];
#pragma unroll
        for (int tt = 0; tt < TTB; ++tt) {
          const float4 v = iv[tt * (I / 4) + k4];  // uniform address -> LDS broadcast
          xg[tt] = dot4(w4, v, xg[tt]);
        }
      }
#pragma unroll
      for (int tt = 0; tt < TTB; ++tt) xg_all[tt * NG + tid] = xg[tt];
      __syncthreads();
    }

    // ---- sequential timesteps ----
#pragma unroll 1
    for (int tt = 0; tt < TTB; ++tt) {
      const int t = chunk * TTB + tt;
      const int p = t & 1;

      // recurrent partial dot: 4 gates over this thread's k-quarter
      float a0 = 0.f, a1 = 0.f, a2 = 0.f, a3 = 0.f;
      const float4* hv = reinterpret_cast<const float4*>(&hbuf[p][kq][0]);
#pragma unroll
      for (int r = 0; r < 8; ++r) {
        const float4 h4 = hv[r];
        a0 = dot4(wh[0][r], h4, a0);
        a1 = dot4(wh[1][r], h4, a1);
        a2 = dot4(wh[2][r], h4, a2);
        a3 = dot4(wh[3][r], h4, a3);
      }
      // quad butterfly reduce over kq (all 4 lanes end with the full sums)
      a0 += __shfl_xor(a0, 1, 4); a0 += __shfl_xor(a0, 2, 4);
      a1 += __shfl_xor(a1, 1, 4); a1 += __shfl_xor(a1, 2, 4);
      a2 += __shfl_xor(a2, 1, 4); a2 += __shfl_xor(a2, 2, 4);
      a3 += __shfl_xor(a3, 1, 4); a3 += __shfl_xor(a3, 2, 4);

      const int xbase = (MODE == 2 ? 0 : tt * NG) + j;
      const float pi = a0 + xg_all[xbase];
      const float pf = a1 + xg_all[xbase + 128];
      const float pg = a2 + xg_all[xbase + 256];
      const float po = a3 + xg_all[xbase + 384];

      const float ig = sigm(pi);
      const float fg = sigm(pf);
      const float gg = tanh_(pg);
      const float og = sigm(po);
      c = fmaf(fg, c, ig * gg);
      const float h = og * tanh_(c);

      if (kq == 0) {
        hbuf[p ^ 1][j >> 5][j & 31] = h;
        if (MODE == 0 || MODE == 2) seq_out[((size_t)b * NT + t) * NH + j] = h;
        if (MODE == 1 && t == NT - 1) hT_out[(size_t)b * NH + j] = h;
      }
      __syncthreads();  // h(t+1) visible; hbuf[p] free for overwrite next step

      if (MODE == 3) {
        // fused output projection: out[b,t,f] = W_out[f,:].h + b_out[f]
        if (tid < 128) {
          const int f = tid & 63, kh = tid >> 6;
          float acc = 0.f;
          const float4* wrow = reinterpret_cast<const float4*>(Wout + (size_t)f * NH + kh * 64);
#pragma unroll
          for (int k4 = 0; k4 < 16; ++k4) {
            const int k = kh * 64 + k4 * 4;
            const float4 w4 = wrow[k4];
            const float4 h4 = *reinterpret_cast<const float4*>(&hbuf[p ^ 1][k >> 5][k & 31]);
            acc = dot4(w4, h4, acc);
          }
          psum[tid] = acc;
        }
        __syncthreads();
        if (tid < NF) {
          proj_out[((size_t)b * NT + t) * NF + tid] = psum[tid] + psum[tid + 64] + bout_reg;
        }
      }
    }
  }
}

}  // namespace

extern "C" void kernel_launch(void* const* d_in, const int* in_sizes, int n_in,
                              void* d_out, int out_size, void* d_ws, size_t ws_size,
                              hipStream_t stream) {
  (void)in_sizes; (void)n_in; (void)out_size; (void)ws_size;

  const float* x     = (const float*)d_in[0];
  const float* e0Wih = (const float*)d_in[1];
  const float* e0Whh = (const float*)d_in[2];
  const float* e0bih = (const float*)d_in[3];
  const float* e0bhh = (const float*)d_in[4];
  const float* e1Wih = (const float*)d_in[5];
  const float* e1Whh = (const float*)d_in[6];
  const float* e1bih = (const float*)d_in[7];
  const float* e1bhh = (const float*)d_in[8];
  const float* d0Wih = (const float*)d_in[9];
  const float* d0Whh = (const float*)d_in[10];
  const float* d0bih = (const float*)d_in[11];
  const float* d0bhh = (const float*)d_in[12];
  const float* d1Wih = (const float*)d_in[13];
  const float* d1Whh = (const float*)d_in[14];
  const float* d1bih = (const float*)d_in[15];
  const float* d1bhh = (const float*)d_in[16];
  const float* Wout  = (const float*)d_in[17];
  const float* bout  = (const float*)d_in[18];
  float* out = (float*)d_out;

  // workspace: h-sequence buffer [NB,NT,NH] (reused enc0-out then dec0-out) + hT [NB,NH]
  float* seqA = (float*)d_ws;
  float* hT   = seqA + (size_t)NB * NT * NH;

  dim3 grid(NB), blk(512);
  // encoder layer 0: x -> seqA
  lstm_kernel<64, 0><<<grid, blk, 0, stream>>>(x, nullptr, e0Wih, e0Whh, e0bih, e0bhh,
                                               nullptr, nullptr, seqA, nullptr, nullptr);
  // encoder layer 1: seqA -> hT
  lstm_kernel<128, 1><<<grid, blk, 0, stream>>>(seqA, nullptr, e1Wih, e1Whh, e1bih, e1bhh,
                                                nullptr, nullptr, nullptr, hT, nullptr);
  // decoder layer 0: broadcast(hT) -> seqA (input contribution constant over t)
  lstm_kernel<128, 2><<<grid, blk, 0, stream>>>(nullptr, hT, d0Wih, d0Whh, d0bih, d0bhh,
                                                nullptr, nullptr, seqA, nullptr, nullptr);
  // decoder layer 1 + fused projection: seqA -> out
  lstm_kernel<128, 3><<<grid, blk, 0, stream>>>(seqA, nullptr, d1Wih, d1Whh, d1bih, d1bhh,
                                                Wout, bout, nullptr, nullptr, out);
}

// Round 2
// 2919.408 us; speedup vs baseline: 1.2272x; 1.2272x over previous
//
#include <hip/hip_runtime.h>
#include <cstddef>

namespace {

typedef _Float16 half_t;
typedef _Float16 half2_t __attribute__((ext_vector_type(2)));

constexpr int NB = 256;  // batch
constexpr int NT = 512;  // time
constexpr int NF = 64;   // feature
constexpr int NH = 128;  // hidden
constexpr int NG = 512;  // 4*NH gates

__device__ __forceinline__ float sigm(float x) { return 1.0f / (1.0f + __expf(-x)); }
__device__ __forceinline__ float tanh_(float x) { return 2.0f / (1.0f + __expf(-2.0f * x)) - 1.0f; }

__device__ __forceinline__ float fdot2(half2_t a, half2_t b, float c) {
#if __has_builtin(__builtin_amdgcn_fdot2)
  return __builtin_amdgcn_fdot2(a, b, c, false);  // v_dot2_f32_f16, fp32 accumulate
#else
  return c + (float)a[0] * (float)b[0] + (float)a[1] * (float)b[1];
#endif
}

// fp32 -> fp16 weight/copy conversion (prep pass into workspace)
__global__ void cvt_kernel(const float* __restrict__ s, half_t* __restrict__ d, int n4) {
  int i = blockIdx.x * blockDim.x + threadIdx.x;
  if (i < n4) {
    float4 v = reinterpret_cast<const float4*>(s)[i];
    half2_t lo = {(half_t)v.x, (half_t)v.y};
    half2_t hi = {(half_t)v.z, (half_t)v.w};
    reinterpret_cast<half2_t*>(d)[2 * i] = lo;
    reinterpret_cast<half2_t*>(d)[2 * i + 1] = hi;
  }
}

// MODE: 0 = fp32 seq-in -> fp16 seq-out      (enc layer 0)
//       1 = fp16 seq-in -> fp32 hT-out       (enc layer 1)
//       2 = fp32 hT-in  -> fp16 seq-out      (dec layer 0; input const over t)
//       3 = fp16 seq-in -> fused projection  (dec layer 1 + W_out)
// One block per batch element, 512 threads (8 waves).
// Gate order: i=[0,128), f=[128,256), g=[256,384), o=[384,512).
template <int I, int MODE>
__global__ __launch_bounds__(512, 1) void lstm_kernel(
    const float* __restrict__ in_f,    // [NB,NT,I] fp32 (mode 0)
    const half_t* __restrict__ in_h,   // [NB,NT,I] fp16 (modes 1,3)
    const float* __restrict__ hT_in,   // [NB,NH]   (mode 2)
    const half_t* __restrict__ Wih,    // [NG,I]  fp16
    const half_t* __restrict__ Whh,    // [NG,NH] fp16
    const float* __restrict__ bih,
    const float* __restrict__ bhh,
    const half_t* __restrict__ Wout,   // [NF,NH] fp16 (mode 3)
    const float* __restrict__ bout,    // [NF]         (mode 3)
    half_t* __restrict__ seq_out,      // [NB,NT,NH] fp16 (modes 0,2)
    float* __restrict__ hT_out,        // [NB,NH]        (mode 1)
    float* __restrict__ proj_out)      // [NB,NT,NF]     (mode 3)
{
  constexpr int TTB = (MODE == 2) ? 1 : 16;
  constexpr int NCHUNK = NT / TTB;
  const int b = blockIdx.x;
  const int tid = threadIdx.x;
  const int j = tid >> 2;   // hidden unit [0,128)
  const int kq = tid & 3;   // k-quarter  [0,4)

  // h double-buffer (fp16): quarters padded to 40 halfs (80 B) so quarter bases
  // are 16B-aligned and land on distinct banks {0,20,8,28} -> conflict-free b128.
  __shared__ __align__(16) half_t hbuf[2][4][40];
  __shared__ __align__(16) float xg_all[(MODE == 2 ? 1 : TTB) * NG];
  __shared__ __align__(16) half_t in_lds[(MODE == 2) ? NH : (TTB * I)];

  // Recurrent weights resident: 4 gates x 32 k as 64 half2 VGPRs.
  half2_t wh[4][16];
#pragma unroll
  for (int gi = 0; gi < 4; ++gi) {
    const half2_t* p = reinterpret_cast<const half2_t*>(Whh + (size_t)(gi * NH + j) * NH + kq * 32);
#pragma unroll
    for (int r = 0; r < 16; ++r) wh[gi][r] = p[r];
  }
  const float bias_g = bih[tid] + bhh[tid];

  // Mode-3 persistent projection fragment: row f=tid>>3, k = (tid&7)*16..+16
  half2_t wo[8];
  float breg = 0.0f;
  if (MODE == 3) {
    const int pf = tid >> 3, pk = tid & 7;
    const half2_t* p = reinterpret_cast<const half2_t*>(Wout + (size_t)pf * NH + pk * 16);
#pragma unroll
    for (int r = 0; r < 8; ++r) wo[r] = p[r];
    breg = bout[pf];
  }

  if (tid < NH) hbuf[0][tid >> 5][tid & 31] = (half_t)0.0f;  // h0 = 0
  float c = 0.0f;                                            // c0 = 0 (replicated x4 lanes)

  if (MODE == 2) {
    // Constant input contribution: xg[g] = bias + W_ih[g,:] . hT[b,:]
    if (tid < NH) in_lds[tid] = (half_t)hT_in[(size_t)b * NH + tid];
    __syncthreads();
    const half2_t* wr = reinterpret_cast<const half2_t*>(Wih + (size_t)tid * NH);
    const half2_t* hv = reinterpret_cast<const half2_t*>(in_lds);
    float a0 = bias_g, a1 = 0.f, a2 = 0.f, a3 = 0.f;
#pragma unroll
    for (int k = 0; k < 16; ++k) {
      a0 = fdot2(wr[4 * k + 0], hv[4 * k + 0], a0);
      a1 = fdot2(wr[4 * k + 1], hv[4 * k + 1], a1);
      a2 = fdot2(wr[4 * k + 2], hv[4 * k + 2], a2);
      a3 = fdot2(wr[4 * k + 3], hv[4 * k + 3], a3);
    }
    xg_all[tid] = (a0 + a1) + (a2 + a3);
    __syncthreads();
  }

  for (int chunk = 0; chunk < NCHUNK; ++chunk) {
    if (MODE != 2) {
      // ---- stage input chunk into LDS as fp16 ----
      if (MODE == 0) {
        const float4* src4 =
            reinterpret_cast<const float4*>(in_f + ((size_t)b * NT + (size_t)chunk * TTB) * I);
        half2_t* dst = reinterpret_cast<half2_t*>(in_lds);
        for (int i = tid; i < TTB * I / 4; i += 512) {
          float4 v = src4[i];
          dst[2 * i]     = {(half_t)v.x, (half_t)v.y};
          dst[2 * i + 1] = {(half_t)v.z, (half_t)v.w};
        }
      } else {
        const unsigned int* srcu =
            reinterpret_cast<const unsigned int*>(in_h + ((size_t)b * NT + (size_t)chunk * TTB) * I);
        unsigned int* dstu = reinterpret_cast<unsigned int*>(in_lds);
        for (int i = tid; i < TTB * I / 2; i += 512) dstu[i] = srcu[i];
      }
      __syncthreads();

      // ---- input GEMM for this chunk: thread == gate, W_ih row streamed from L2 ----
      float xg[TTB];
#pragma unroll
      for (int tt = 0; tt < TTB; ++tt) xg[tt] = bias_g;
      const half2_t* wr = reinterpret_cast<const half2_t*>(Wih + (size_t)tid * I);
      const half2_t* iv = reinterpret_cast<const half2_t*>(in_lds);
#pragma unroll 2
      for (int k2 = 0; k2 < I / 2; ++k2) {
        const half2_t w2 = wr[k2];
#pragma unroll
        for (int tt = 0; tt < TTB; ++tt) {
          xg[tt] = fdot2(w2, iv[tt * (I / 2) + k2], xg[tt]);  // uniform addr -> LDS broadcast
        }
      }
#pragma unroll
      for (int tt = 0; tt < TTB; ++tt) xg_all[tt * NG + tid] = xg[tt];
      __syncthreads();
    }

    // ---- sequential timesteps ----
#pragma unroll 1
    for (int tt = 0; tt < TTB; ++tt) {
      const int t = chunk * TTB + tt;
      const int p = t & 1;

      float a0 = 0.f, a1 = 0.f, a2 = 0.f, a3 = 0.f;
      const half2_t* hv = reinterpret_cast<const half2_t*>(&hbuf[p][kq][0]);
#pragma unroll
      for (int r = 0; r < 16; ++r) {
        const half2_t h2 = hv[r];
        a0 = fdot2(wh[0][r], h2, a0);
        a1 = fdot2(wh[1][r], h2, a1);
        a2 = fdot2(wh[2][r], h2, a2);
        a3 = fdot2(wh[3][r], h2, a3);
      }
      a0 += __shfl_xor(a0, 1, 4); a0 += __shfl_xor(a0, 2, 4);
      a1 += __shfl_xor(a1, 1, 4); a1 += __shfl_xor(a1, 2, 4);
      a2 += __shfl_xor(a2, 1, 4); a2 += __shfl_xor(a2, 2, 4);
      a3 += __shfl_xor(a3, 1, 4); a3 += __shfl_xor(a3, 2, 4);

      const int xbase = (MODE == 2 ? 0 : tt * NG) + j;
      const float pi = a0 + xg_all[xbase];
      const float pf_ = a1 + xg_all[xbase + 128];
      const float pg = a2 + xg_all[xbase + 256];
      const float po = a3 + xg_all[xbase + 384];

      const float ig = sigm(pi);
      const float fg = sigm(pf_);
      const float gg = tanh_(pg);
      const float og = sigm(po);
      c = fmaf(fg, c, ig * gg);
      const float h = og * tanh_(c);

      if (kq == 0) {
        hbuf[p ^ 1][j >> 5][j & 31] = (half_t)h;
        if (MODE == 0 || MODE == 2) seq_out[((size_t)b * NT + t) * NH + j] = (half_t)h;
        if (MODE == 1 && t == NT - 1) hT_out[(size_t)b * NH + j] = h;
      }
      __syncthreads();  // h(t+1) visible; hbuf[p] free next step

      if (MODE == 3) {
        // fused projection, all 512 threads: f=tid>>3 (64 rows), k-split 8x16.
        const int pk = tid & 7;
        const half2_t* hv2 =
            reinterpret_cast<const half2_t*>(&hbuf[p ^ 1][pk >> 1][(pk & 1) * 16]);
        float acc = 0.f;
#pragma unroll
        for (int r = 0; r < 8; ++r) acc = fdot2(wo[r], hv2[r], acc);
        acc += __shfl_xor(acc, 1, 8);
        acc += __shfl_xor(acc, 2, 8);
        acc += __shfl_xor(acc, 4, 8);
        if (pk == 0) proj_out[((size_t)b * NT + t) * NF + (tid >> 3)] = acc + breg;
      }
    }
  }
}

}  // namespace

extern "C" void kernel_launch(void* const* d_in, const int* in_sizes, int n_in,
                              void* d_out, int out_size, void* d_ws, size_t ws_size,
                              hipStream_t stream) {
  (void)in_sizes; (void)n_in; (void)out_size; (void)ws_size;

  const float* x     = (const float*)d_in[0];
  const float* e0Wih = (const float*)d_in[1];
  const float* e0Whh = (const float*)d_in[2];
  const float* e0bih = (const float*)d_in[3];
  const float* e0bhh = (const float*)d_in[4];
  const float* e1Wih = (const float*)d_in[5];
  const float* e1Whh = (const float*)d_in[6];
  const float* e1bih = (const float*)d_in[7];
  const float* e1bhh = (const float*)d_in[8];
  const float* d0Wih = (const float*)d_in[9];
  const float* d0Whh = (const float*)d_in[10];
  const float* d0bih = (const float*)d_in[11];
  const float* d0bhh = (const float*)d_in[12];
  const float* d1Wih = (const float*)d_in[13];
  const float* d1Whh = (const float*)d_in[14];
  const float* d1bih = (const float*)d_in[15];
  const float* d1bhh = (const float*)d_in[16];
  const float* Wout  = (const float*)d_in[17];
  const float* bout  = (const float*)d_in[18];
  float* out = (float*)d_out;

  // ---- workspace layout (fp16 weights + fp16 inter-layer seq + fp32 hT) ----
  half_t* e0Wih_h = (half_t*)d_ws;               // 512*64
  half_t* e1Wih_h = e0Wih_h + 512 * 64;          // 512*128
  half_t* d0Wih_h = e1Wih_h + 512 * 128;
  half_t* d1Wih_h = d0Wih_h + 512 * 128;
  half_t* e0Whh_h = d1Wih_h + 512 * 128;
  half_t* e1Whh_h = e0Whh_h + 512 * 128;
  half_t* d0Whh_h = e1Whh_h + 512 * 128;
  half_t* d1Whh_h = d0Whh_h + 512 * 128;
  half_t* Wout_h  = d1Whh_h + 512 * 128;         // 64*128
  half_t* seqA_h  = Wout_h + 64 * 128;           // NB*NT*NH fp16
  float*  hT      = (float*)(seqA_h + (size_t)NB * NT * NH);

  auto cvt = [&](const float* s, half_t* d, int n) {
    int n4 = n / 4;
    cvt_kernel<<<(n4 + 255) / 256, 256, 0, stream>>>(s, d, n4);
  };
  cvt(e0Wih, e0Wih_h, 512 * 64);
  cvt(e1Wih, e1Wih_h, 512 * 128);
  cvt(d0Wih, d0Wih_h, 512 * 128);
  cvt(d1Wih, d1Wih_h, 512 * 128);
  cvt(e0Whh, e0Whh_h, 512 * 128);
  cvt(e1Whh, e1Whh_h, 512 * 128);
  cvt(d0Whh, d0Whh_h, 512 * 128);
  cvt(d1Whh, d1Whh_h, 512 * 128);
  cvt(Wout, Wout_h, 64 * 128);

  dim3 grid(NB), blk(512);
  // encoder layer 0: x (fp32) -> seqA (fp16)
  lstm_kernel<64, 0><<<grid, blk, 0, stream>>>(x, nullptr, nullptr, e0Wih_h, e0Whh_h,
                                               e0bih, e0bhh, nullptr, nullptr,
                                               seqA_h, nullptr, nullptr);
  // encoder layer 1: seqA -> hT (fp32)
  lstm_kernel<128, 1><<<grid, blk, 0, stream>>>(nullptr, seqA_h, nullptr, e1Wih_h, e1Whh_h,
                                                e1bih, e1bhh, nullptr, nullptr,
                                                nullptr, hT, nullptr);
  // decoder layer 0: broadcast(hT) -> seqA (fp16); input contribution const over t
  lstm_kernel<128, 2><<<grid, blk, 0, stream>>>(nullptr, nullptr, hT, d0Wih_h, d0Whh_h,
                                                d0bih, d0bhh, nullptr, nullptr,
                                                seqA_h, nullptr, nullptr);
  // decoder layer 1 + fused projection: seqA -> out (fp32)
  lstm_kernel<128, 3><<<grid, blk, 0, stream>>>(nullptr, seqA_h, nullptr, d1Wih_h, d1Whh_h,
                                                d1bih, d1bhh, Wout_h, bout,
                                                nullptr, nullptr, out);
}

// Round 3
// 2201.878 us; speedup vs baseline: 1.6271x; 1.3259x over previous
//
#include <hip/hip_runtime.h>
#include <cstddef>

namespace {

typedef _Float16 half_t;
typedef _Float16 half2_t __attribute__((ext_vector_type(2)));
typedef _Float16 half8_t __attribute__((ext_vector_type(8)));

constexpr int NB = 256;  // batch
constexpr int NT = 512;  // time
constexpr int NF = 64;   // feature
constexpr int NH = 128;  // hidden
constexpr int NG = 512;  // 4*NH gates

__device__ __forceinline__ float sigm(float x) { return 1.0f / (1.0f + __expf(-x)); }
__device__ __forceinline__ float tanh_(float x) { return 2.0f / (1.0f + __expf(-2.0f * x)) - 1.0f; }

__device__ __forceinline__ float fdot2(half2_t a, half2_t b, float c) {
  return __builtin_amdgcn_fdot2(a, b, c, false);  // v_dot2_f32_f16, fp32 accumulate
}

// Pin a value into a VGPR: asm output cannot be rematerialized by reloading.
__device__ __forceinline__ void pinv(half2_t& x) { asm volatile("" : "+v"(x)); }

// fp32 -> fp16 weight conversion (prep pass into workspace)
__global__ void cvt_kernel(const float* __restrict__ s, half_t* __restrict__ d, int n4) {
  int i = blockIdx.x * blockDim.x + threadIdx.x;
  if (i < n4) {
    float4 v = reinterpret_cast<const float4*>(s)[i];
    half2_t lo = {(half_t)v.x, (half_t)v.y};
    half2_t hi = {(half_t)v.z, (half_t)v.w};
    reinterpret_cast<half2_t*>(d)[2 * i] = lo;
    reinterpret_cast<half2_t*>(d)[2 * i + 1] = hi;
  }
}

// MODE: 0 = fp32 seq-in -> fp16 seq-out      (enc layer 0)
//       1 = fp16 seq-in -> fp32 hT-out       (enc layer 1)
//       2 = fp32 hT-in  -> fp16 seq-out      (dec layer 0; input const over t)
//       3 = fp16 seq-in -> fused projection  (dec layer 1 + W_out)
// One block per batch element, 512 threads (8 waves, 2/SIMD).
// Gate order: i=[0,128), f=[128,256), g=[256,384), o=[384,512).
template <int I, int MODE>
__global__ __launch_bounds__(512, 2) void lstm_kernel(
    const float* __restrict__ in_f,    // [NB,NT,I] fp32 (mode 0)
    const half_t* __restrict__ in_h,   // [NB,NT,I] fp16 (modes 1,3)
    const float* __restrict__ hT_in,   // [NB,NH]   (mode 2)
    const half_t* __restrict__ Wih,    // [NG,I]  fp16
    const half_t* __restrict__ Whh,    // [NG,NH] fp16
    const float* __restrict__ bih,
    const float* __restrict__ bhh,
    const half_t* __restrict__ Wout,   // [NF,NH] fp16 (mode 3)
    const float* __restrict__ bout,    // [NF]         (mode 3)
    half_t* __restrict__ seq_out,      // [NB,NT,NH] fp16 (modes 0,2)
    float* __restrict__ hT_out,        // [NB,NH]        (mode 1)
    float* __restrict__ proj_out)      // [NB,NT,NF]     (mode 3)
{
  constexpr int TTB = (MODE == 2) ? 1 : 16;
  constexpr int NCHUNK = NT / TTB;
  const int b = blockIdx.x;
  const int tid = threadIdx.x;
  const int j = tid >> 2;   // hidden unit [0,128)
  const int kq = tid & 3;   // k-quarter  [0,4)

  // h double-buffer (fp16): quarters padded to 40 halfs (80 B = 5*16B) so quarter
  // bases are 16B-aligned and land on distinct bank groups -> conflict-free b128.
  __shared__ __align__(16) half_t hbuf[2][4][40];
  __shared__ __align__(16) float xg_all[(MODE == 2 ? 1 : TTB) * NG];
  __shared__ __align__(16) half_t in_lds[(MODE == 2) ? NH : (TTB * I)];

  // ---- resident weights (asm-pinned so the allocator can't sink the loads) ----
  // Recurrent: 4 gates x 32 k as 64 half2 VGPRs.
  half2_t wh[4][16];
#pragma unroll
  for (int gi = 0; gi < 4; ++gi) {
    const half2_t* p = reinterpret_cast<const half2_t*>(Whh + (size_t)(gi * NH + j) * NH + kq * 32);
#pragma unroll
    for (int r = 0; r < 16; ++r) wh[gi][r] = p[r];
  }
#pragma unroll
  for (int gi = 0; gi < 4; ++gi)
#pragma unroll
    for (int r = 0; r < 16; ++r) pinv(wh[gi][r]);

  // Input-GEMM row: W_ih[tid,:] reused across all 32 chunks.
  half2_t wi[I / 2];
  if (MODE != 2) {
    const half2_t* p = reinterpret_cast<const half2_t*>(Wih + (size_t)tid * I);
#pragma unroll
    for (int r = 0; r < I / 2; ++r) wi[r] = p[r];
#pragma unroll
    for (int r = 0; r < I / 2; ++r) pinv(wi[r]);
  }

  const float bias_g = bih[tid] + bhh[tid];

  // Mode-3 projection fragment: row f=tid>>3, k = (tid&7)*16..+16
  half2_t wo[8];
  float breg = 0.0f;
  if (MODE == 3) {
    const int pf = tid >> 3, pk = tid & 7;
    const half2_t* p = reinterpret_cast<const half2_t*>(Wout + (size_t)pf * NH + pk * 16);
#pragma unroll
    for (int r = 0; r < 8; ++r) wo[r] = p[r];
#pragma unroll
    for (int r = 0; r < 8; ++r) pinv(wo[r]);
    breg = bout[pf];
  }

  if (tid < NH) hbuf[0][tid >> 5][tid & 31] = (half_t)0.0f;  // h0 = 0
  float c = 0.0f;                                            // c0 = 0 (replicated x4 lanes)

  if (MODE == 2) {
    // Constant input contribution: xg[g] = bias + W_ih[g,:] . hT[b,:]
    if (tid < NH) in_lds[tid] = (half_t)hT_in[(size_t)b * NH + tid];
    __syncthreads();
    const half2_t* wr = reinterpret_cast<const half2_t*>(Wih + (size_t)tid * NH);
    const half2_t* hv = reinterpret_cast<const half2_t*>(in_lds);
    float a0 = bias_g, a1 = 0.f, a2 = 0.f, a3 = 0.f;
#pragma unroll
    for (int k = 0; k < 16; ++k) {
      a0 = fdot2(wr[4 * k + 0], hv[4 * k + 0], a0);
      a1 = fdot2(wr[4 * k + 1], hv[4 * k + 1], a1);
      a2 = fdot2(wr[4 * k + 2], hv[4 * k + 2], a2);
      a3 = fdot2(wr[4 * k + 3], hv[4 * k + 3], a3);
    }
    xg_all[tid] = (a0 + a1) + (a2 + a3);
    __syncthreads();
  }

  for (int chunk = 0; chunk < NCHUNK; ++chunk) {
    if (MODE != 2) {
      // ---- stage input chunk into LDS as fp16 ----
      if (MODE == 0) {
        const float4* src4 =
            reinterpret_cast<const float4*>(in_f + ((size_t)b * NT + (size_t)chunk * TTB) * I);
        half2_t* dst = reinterpret_cast<half2_t*>(in_lds);
        for (int i = tid; i < TTB * I / 4; i += 512) {
          float4 v = src4[i];
          half2_t lo = {(half_t)v.x, (half_t)v.y};
          half2_t hi = {(half_t)v.z, (half_t)v.w};
          dst[2 * i] = lo;
          dst[2 * i + 1] = hi;
        }
      } else {
        const unsigned int* srcu =
            reinterpret_cast<const unsigned int*>(in_h + ((size_t)b * NT + (size_t)chunk * TTB) * I);
        unsigned int* dstu = reinterpret_cast<unsigned int*>(in_lds);
        for (int i = tid; i < TTB * I / 2; i += 512) dstu[i] = srcu[i];
      }
      __syncthreads();

      // ---- input GEMM: thread == gate, resident wi row, uniform b128 LDS reads ----
      const half8_t* iv8 = reinterpret_cast<const half8_t*>(in_lds);
#pragma unroll
      for (int tt = 0; tt < TTB; ++tt) {
        float acc = bias_g;
#pragma unroll
        for (int k8 = 0; k8 < I / 8; ++k8) {
          half8_t v = iv8[tt * (I / 8) + k8];
          half2_t v0 = {v[0], v[1]}, v1 = {v[2], v[3]}, v2 = {v[4], v[5]}, v3 = {v[6], v[7]};
          acc = fdot2(wi[4 * k8 + 0], v0, acc);
          acc = fdot2(wi[4 * k8 + 1], v1, acc);
          acc = fdot2(wi[4 * k8 + 2], v2, acc);
          acc = fdot2(wi[4 * k8 + 3], v3, acc);
        }
        xg_all[tt * NG + tid] = acc;
      }
      __syncthreads();
    }

    // ---- sequential timesteps ----
#pragma unroll 1
    for (int tt = 0; tt < TTB; ++tt) {
      const int t = chunk * TTB + tt;
      const int p = t & 1;

      float a0 = 0.f, a1 = 0.f, a2 = 0.f, a3 = 0.f;
      const half8_t* hv8 = reinterpret_cast<const half8_t*>(&hbuf[p][kq][0]);
#pragma unroll
      for (int r8 = 0; r8 < 4; ++r8) {
        half8_t h8 = hv8[r8];
        half2_t h0 = {h8[0], h8[1]}, h1 = {h8[2], h8[3]};
        half2_t h2 = {h8[4], h8[5]}, h3 = {h8[6], h8[7]};
        a0 = fdot2(wh[0][4 * r8 + 0], h0, a0); a0 = fdot2(wh[0][4 * r8 + 1], h1, a0);
        a0 = fdot2(wh[0][4 * r8 + 2], h2, a0); a0 = fdot2(wh[0][4 * r8 + 3], h3, a0);
        a1 = fdot2(wh[1][4 * r8 + 0], h0, a1); a1 = fdot2(wh[1][4 * r8 + 1], h1, a1);
        a1 = fdot2(wh[1][4 * r8 + 2], h2, a1); a1 = fdot2(wh[1][4 * r8 + 3], h3, a1);
        a2 = fdot2(wh[2][4 * r8 + 0], h0, a2); a2 = fdot2(wh[2][4 * r8 + 1], h1, a2);
        a2 = fdot2(wh[2][4 * r8 + 2], h2, a2); a2 = fdot2(wh[2][4 * r8 + 3], h3, a2);
        a3 = fdot2(wh[3][4 * r8 + 0], h0, a3); a3 = fdot2(wh[3][4 * r8 + 1], h1, a3);
        a3 = fdot2(wh[3][4 * r8 + 2], h2, a3); a3 = fdot2(wh[3][4 * r8 + 3], h3, a3);
      }
      a0 += __shfl_xor(a0, 1, 4); a0 += __shfl_xor(a0, 2, 4);
      a1 += __shfl_xor(a1, 1, 4); a1 += __shfl_xor(a1, 2, 4);
      a2 += __shfl_xor(a2, 1, 4); a2 += __shfl_xor(a2, 2, 4);
      a3 += __shfl_xor(a3, 1, 4); a3 += __shfl_xor(a3, 2, 4);

      const int xbase = (MODE == 2 ? 0 : tt * NG) + j;
      const float pi = a0 + xg_all[xbase];
      const float pf_ = a1 + xg_all[xbase + 128];
      const float pg = a2 + xg_all[xbase + 256];
      const float po = a3 + xg_all[xbase + 384];

      const float ig = sigm(pi);
      const float fg = sigm(pf_);
      const float gg = tanh_(pg);
      const float og = sigm(po);
      c = fmaf(fg, c, ig * gg);
      const float h = og * tanh_(c);

      if (kq == 0) {
        hbuf[p ^ 1][j >> 5][j & 31] = (half_t)h;
        if (MODE == 0 || MODE == 2) seq_out[((size_t)b * NT + t) * NH + j] = (half_t)h;
        if (MODE == 1 && t == NT - 1) hT_out[(size_t)b * NH + j] = h;
      }
      __syncthreads();  // h(t+1) visible; hbuf[p] free next step

      if (MODE == 3) {
        // fused projection, all 512 threads: f=tid>>3 (64 rows), k-split 8x16.
        const int pk = tid & 7;
        const half8_t* hp8 =
            reinterpret_cast<const half8_t*>(&hbuf[p ^ 1][pk >> 1][0]) + (pk & 1) * 2;
        half8_t u0 = hp8[0], u1 = hp8[1];
        float acc = 0.f;
        half2_t q0 = {u0[0], u0[1]}, q1 = {u0[2], u0[3]};
        half2_t q2 = {u0[4], u0[5]}, q3 = {u0[6], u0[7]};
        half2_t q4 = {u1[0], u1[1]}, q5 = {u1[2], u1[3]};
        half2_t q6 = {u1[4], u1[5]}, q7 = {u1[6], u1[7]};
        acc = fdot2(wo[0], q0, acc); acc = fdot2(wo[1], q1, acc);
        acc = fdot2(wo[2], q2, acc); acc = fdot2(wo[3], q3, acc);
        acc = fdot2(wo[4], q4, acc); acc = fdot2(wo[5], q5, acc);
        acc = fdot2(wo[6], q6, acc); acc = fdot2(wo[7], q7, acc);
        acc += __shfl_xor(acc, 1, 8);
        acc += __shfl_xor(acc, 2, 8);
        acc += __shfl_xor(acc, 4, 8);
        if (pk == 0) proj_out[((size_t)b * NT + t) * NF + (tid >> 3)] = acc + breg;
      }
    }
  }
}

}  // namespace

extern "C" void kernel_launch(void* const* d_in, const int* in_sizes, int n_in,
                              void* d_out, int out_size, void* d_ws, size_t ws_size,
                              hipStream_t stream) {
  (void)in_sizes; (void)n_in; (void)out_size; (void)ws_size;

  const float* x     = (const float*)d_in[0];
  const float* e0Wih = (const float*)d_in[1];
  const float* e0Whh = (const float*)d_in[2];
  const float* e0bih = (const float*)d_in[3];
  const float* e0bhh = (const float*)d_in[4];
  const float* e1Wih = (const float*)d_in[5];
  const float* e1Whh = (const float*)d_in[6];
  const float* e1bih = (const float*)d_in[7];
  const float* e1bhh = (const float*)d_in[8];
  const float* d0Wih = (const float*)d_in[9];
  const float* d0Whh = (const float*)d_in[10];
  const float* d0bih = (const float*)d_in[11];
  const float* d0bhh = (const float*)d_in[12];
  const float* d1Wih = (const float*)d_in[13];
  const float* d1Whh = (const float*)d_in[14];
  const float* d1bih = (const float*)d_in[15];
  const float* d1bhh = (const float*)d_in[16];
  const float* Wout  = (const float*)d_in[17];
  const float* bout  = (const float*)d_in[18];
  float* out = (float*)d_out;

  // ---- workspace layout (fp16 weights + fp16 inter-layer seq + fp32 hT) ----
  half_t* e0Wih_h = (half_t*)d_ws;               // 512*64
  half_t* e1Wih_h = e0Wih_h + 512 * 64;          // 512*128
  half_t* d0Wih_h = e1Wih_h + 512 * 128;
  half_t* d1Wih_h = d0Wih_h + 512 * 128;
  half_t* e0Whh_h = d1Wih_h + 512 * 128;
  half_t* e1Whh_h = e0Whh_h + 512 * 128;
  half_t* d0Whh_h = e1Whh_h + 512 * 128;
  half_t* d1Whh_h = d0Whh_h + 512 * 128;
  half_t* Wout_h  = d1Whh_h + 512 * 128;         // 64*128
  half_t* seqA_h  = Wout_h + 64 * 128;           // NB*NT*NH fp16
  float*  hT      = (float*)(seqA_h + (size_t)NB * NT * NH);

  auto cvt = [&](const float* s, half_t* d, int n) {
    int n4 = n / 4;
    cvt_kernel<<<(n4 + 255) / 256, 256, 0, stream>>>(s, d, n4);
  };
  cvt(e0Wih, e0Wih_h, 512 * 64);
  cvt(e1Wih, e1Wih_h, 512 * 128);
  cvt(d0Wih, d0Wih_h, 512 * 128);
  cvt(d1Wih, d1Wih_h, 512 * 128);
  cvt(e0Whh, e0Whh_h, 512 * 128);
  cvt(e1Whh, e1Whh_h, 512 * 128);
  cvt(d0Whh, d0Whh_h, 512 * 128);
  cvt(d1Whh, d1Whh_h, 512 * 128);
  cvt(Wout, Wout_h, 64 * 128);

  dim3 grid(NB), blk(512);
  // encoder layer 0: x (fp32) -> seqA (fp16)
  lstm_kernel<64, 0><<<grid, blk, 0, stream>>>(x, nullptr, nullptr, e0Wih_h, e0Whh_h,
                                               e0bih, e0bhh, nullptr, nullptr,
                                               seqA_h, nullptr, nullptr);
  // encoder layer 1: seqA -> hT (fp32)
  lstm_kernel<128, 1><<<grid, blk, 0, stream>>>(nullptr, seqA_h, nullptr, e1Wih_h, e1Whh_h,
                                                e1bih, e1bhh, nullptr, nullptr,
                                                nullptr, hT, nullptr);
  // decoder layer 0: broadcast(hT) -> seqA (fp16); input contribution const over t
  lstm_kernel<128, 2><<<grid, blk, 0, stream>>>(nullptr, nullptr, hT, d0Wih_h, d0Whh_h,
                                                d0bih, d0bhh, nullptr, nullptr,
                                                seqA_h, nullptr, nullptr);
  // decoder layer 1 + fused projection: seqA -> out (fp32)
  lstm_kernel<128, 3><<<grid, blk, 0, stream>>>(nullptr, seqA_h, nullptr, d1Wih_h, d1Whh_h,
                                                d1bih, d1bhh, Wout_h, bout,
                                                nullptr, nullptr, out);
}

// Round 4
// 1984.486 us; speedup vs baseline: 1.8053x; 1.1095x over previous
//
#include <hip/hip_runtime.h>
#include <cstddef>

namespace {

typedef _Float16 half_t;
typedef _Float16 half2_t __attribute__((ext_vector_type(2)));
typedef _Float16 f16x4 __attribute__((ext_vector_type(4)));
typedef _Float16 f16x8 __attribute__((ext_vector_type(8)));
typedef float f32x4 __attribute__((ext_vector_type(4)));

constexpr int NB = 256;  // batch
constexpr int NT = 512;  // time
constexpr int NH = 128;  // hidden
constexpr int NG = 512;  // 4*NH gates

__device__ __forceinline__ float sigm(float x) { return 1.0f / (1.0f + __expf(-x)); }
__device__ __forceinline__ float tanh_(float x) { return 2.0f / (1.0f + __expf(-2.0f * x)) - 1.0f; }
__device__ __forceinline__ float dot4(float4 w, float4 v, float acc) {
  return fmaf(w.x, v.x, fmaf(w.y, v.y, fmaf(w.z, v.z, fmaf(w.w, v.w, acc))));
}
__device__ __forceinline__ float fdot2(half2_t a, half2_t b, float c) {
  return __builtin_amdgcn_fdot2(a, b, c, false);  // v_dot2_f32_f16, f32 accum
}
__device__ __forceinline__ void pinv(half2_t& x) { asm volatile("" : "+v"(x)); }

// fp32 -> fp16 conversion (Whh prep)
__global__ void cvt_kernel(const float* __restrict__ s, half_t* __restrict__ d, int n4) {
  int i = blockIdx.x * blockDim.x + threadIdx.x;
  if (i < n4) {
    float4 v = reinterpret_cast<const float4*>(s)[i];
    f16x4 hv = {(half_t)v.x, (half_t)v.y, (half_t)v.z, (half_t)v.w};
    reinterpret_cast<f16x4*>(d)[i] = hv;
  }
}

// ============ MFMA GEMM: C[M,Nstr tile] = A[M,K] * B[N,K]^T + b0 + b1 ============
// BM=128, BN=64, 256 threads = 4 waves (each wave: 32 rows x 64 cols, 2x4 frags).
// A: fp32 (AF32) or fp16, row-major [M,K]. B: fp32 row-major [N,K] (weights).
// LDS tiles XOR-swizzled (byte ^= (row&7)<<4) for conflict-free ds_read_b128.
template <int K, bool AF32, bool F32OUT>
__global__ __launch_bounds__(256) void xg_gemm(
    const void* __restrict__ Ap, const float* __restrict__ Bw,
    const float* __restrict__ b0, const float* __restrict__ b1,
    half_t* __restrict__ Ch, float* __restrict__ Cf, int Nstr)
{
  __shared__ __align__(16) half_t Atile[128 * K];
  __shared__ __align__(16) half_t Btile[64 * K];
  const int tid = threadIdx.x;
  const int m0 = blockIdx.x * 128;
  const int n0 = blockIdx.y * 64;
  char* Ab = (char*)Atile;
  char* Bb = (char*)Btile;

  if (AF32) {
    const float* Af = (const float*)Ap;
    for (int idx = tid; idx < 128 * K / 4; idx += 256) {
      int row = idx / (K / 4), o = idx % (K / 4);
      float4 v = *(const float4*)(Af + (size_t)(m0 + row) * K + 4 * o);
      f16x4 hv = {(half_t)v.x, (half_t)v.y, (half_t)v.z, (half_t)v.w};
      int byte = ((row * K + 4 * o) * 2) ^ ((row & 7) << 4);
      *(f16x4*)(Ab + byte) = hv;
    }
  } else {
    const half_t* Ah = (const half_t*)Ap;
    for (int idx = tid; idx < 128 * K / 8; idx += 256) {
      int row = idx / (K / 8), o = idx % (K / 8);
      uint4 v = *(const uint4*)(Ah + (size_t)(m0 + row) * K + 8 * o);
      int byte = ((row * K + 8 * o) * 2) ^ ((row & 7) << 4);
      *(uint4*)(Ab + byte) = v;
    }
  }
  for (int idx = tid; idx < 64 * K / 4; idx += 256) {
    int row = idx / (K / 4), o = idx % (K / 4);
    float4 v = *(const float4*)(Bw + (size_t)(n0 + row) * K + 4 * o);
    f16x4 hv = {(half_t)v.x, (half_t)v.y, (half_t)v.z, (half_t)v.w};
    int byte = ((row * K + 4 * o) * 2) ^ ((row & 7) << 4);
    *(f16x4*)(Bb + byte) = hv;
  }
  __syncthreads();

  const int lane = tid & 63, w = tid >> 6;
  const int r16 = lane & 15, koff = (lane >> 4) * 8;
  f32x4 acc[2][4];
#pragma unroll
  for (int fm = 0; fm < 2; ++fm)
#pragma unroll
    for (int fn = 0; fn < 4; ++fn) acc[fm][fn] = (f32x4){0.f, 0.f, 0.f, 0.f};

#pragma unroll
  for (int ks = 0; ks < K / 32; ++ks) {
    f16x8 a[2], bf[4];
#pragma unroll
    for (int fm = 0; fm < 2; ++fm) {
      int row = w * 32 + fm * 16 + r16;
      int byte = ((row * K + ks * 32 + koff) * 2) ^ ((row & 7) << 4);
      a[fm] = *(const f16x8*)(Ab + byte);
    }
#pragma unroll
    for (int fn = 0; fn < 4; ++fn) {
      int row = fn * 16 + r16;
      int byte = ((row * K + ks * 32 + koff) * 2) ^ ((row & 7) << 4);
      bf[fn] = *(const f16x8*)(Bb + byte);
    }
#pragma unroll
    for (int fm = 0; fm < 2; ++fm)
#pragma unroll
      for (int fn = 0; fn < 4; ++fn)
        acc[fm][fn] = __builtin_amdgcn_mfma_f32_16x16x32_f16(a[fm], bf[fn], acc[fm][fn], 0, 0, 0);
  }

  // D layout: col = lane&15, row = (lane>>4)*4 + q  (m89-verified, dtype-indep)
#pragma unroll
  for (int fm = 0; fm < 2; ++fm)
#pragma unroll
    for (int fn = 0; fn < 4; ++fn) {
      int n = n0 + fn * 16 + r16;
      float bb = (b0 ? b0[n] : 0.f) + (b1 ? b1[n] : 0.f);
#pragma unroll
      for (int q = 0; q < 4; ++q) {
        int m = m0 + w * 32 + fm * 16 + (lane >> 4) * 4 + q;
        float val = acc[fm][fn][q] + bb;
        if (F32OUT) Cf[(size_t)m * Nstr + n] = val;
        else        Ch[(size_t)m * Nstr + n] = (half_t)val;
      }
    }
}

// ============ Recurrent kernel (slim: xg precomputed) ============
// MODE: 0 = xg-stream -> seq-out (enc0, dec1)
//       1 = xg-stream -> hT-out  (enc1)
//       2 = const-xg  -> seq-out (dec0; xg from hT_in, computed once)
// One block per batch element, 512 threads; j=tid>>2 hidden unit, kq=tid&3 k-quarter.
template <int MODE>
__global__ __launch_bounds__(512, 2) void rec_kernel(
    const half_t* __restrict__ xg,     // [NB*NT,NG] fp16 (modes 0/1), biases folded
    const float* __restrict__ hT_in,   // [NB,NH]        (mode 2)
    const float* __restrict__ WihD,    // [NG,NH] fp32   (mode 2)
    const float* __restrict__ bih, const float* __restrict__ bhh,  // (mode 2)
    const half_t* __restrict__ Whh,    // [NG,NH] fp16
    half_t* __restrict__ seq_out,      // [NB,NT,NH] fp16 (modes 0/2)
    float* __restrict__ hT_out)        // [NB,NH]         (mode 1)
{
  const int b = blockIdx.x;
  const int tid = threadIdx.x;
  const int j = tid >> 2;
  const int kq = tid & 3;

  // h double-buffer: quarters padded to 48 halfs (96 B) -> 16B-aligned bases on
  // distinct banks {0,24,16,8}; conflict-free broadcast b128 reads.
  __shared__ __align__(16) half_t hbuf[2][4][48];
  __shared__ __align__(16) half_t xgs[2][8][NG];  // 8-step xg double buffer (modes 0/1)
  __shared__ float xgc[NG];                       // const xg (mode 2)
  __shared__ float hinf[NH];

  // Resident recurrent weights: 4 gates x 32 k as 64 half2 VGPRs (asm-pinned).
  half2_t wh[4][16];
#pragma unroll
  for (int gi = 0; gi < 4; ++gi) {
    const half2_t* p = reinterpret_cast<const half2_t*>(Whh + (size_t)(gi * NH + j) * NH + kq * 32);
#pragma unroll
    for (int r = 0; r < 16; ++r) wh[gi][r] = p[r];
  }
#pragma unroll
  for (int gi = 0; gi < 4; ++gi)
#pragma unroll
    for (int r = 0; r < 16; ++r) pinv(wh[gi][r]);

  if (tid < NH) hbuf[0][tid >> 5][tid & 31] = (half_t)0.0f;  // h0 = 0
  float c = 0.0f;                                            // c0 (replicated x4 kq lanes)

  if (MODE == 2) {
    // one-time: xgc[g] = bih+bhh + Wih[g,:].hT[b,:]  (fp32, thread = gate)
    if (tid < NH) hinf[tid] = hT_in[(size_t)b * NH + tid];
    __syncthreads();
    float a0 = bih[tid] + bhh[tid], a1 = 0.f, a2 = 0.f, a3 = 0.f;
    const float4* wr = (const float4*)(WihD + (size_t)tid * NH);
    const float4* hv = (const float4*)hinf;
#pragma unroll
    for (int k = 0; k < 8; ++k) {
      a0 = dot4(wr[4 * k + 0], hv[4 * k + 0], a0);
      a1 = dot4(wr[4 * k + 1], hv[4 * k + 1], a1);
      a2 = dot4(wr[4 * k + 2], hv[4 * k + 2], a2);
      a3 = dot4(wr[4 * k + 3], hv[4 * k + 3], a3);
    }
    xgc[tid] = (a0 + a1) + (a2 + a3);
    __syncthreads();
  }

  half_t g[8];
  const half_t* xrow = nullptr;
  if (MODE != 2) {
    xrow = xg + (size_t)b * NT * NG + tid;  // thread = gate column
#pragma unroll
    for (int s = 0; s < 8; ++s) g[s] = xrow[(size_t)s * NG];  // chunk 0
  }

  for (int ch = 0; ch < NT / 8; ++ch) {
    if (MODE != 2) {
      // commit staged chunk to LDS; issue loads for next chunk (hidden under 8 steps)
#pragma unroll
      for (int s = 0; s < 8; ++s) xgs[ch & 1][s][tid] = g[s];
      if (ch < NT / 8 - 1) {
#pragma unroll
        for (int s = 0; s < 8; ++s) g[s] = xrow[(size_t)((ch + 1) * 8 + s) * NG];
      }
      __syncthreads();
    }

#pragma unroll 1
    for (int tt = 0; tt < 8; ++tt) {
      const int t = ch * 8 + tt;
      const int p = t & 1;

      float a0 = 0.f, a1 = 0.f, a2 = 0.f, a3 = 0.f;
      const f16x8* hv8 = reinterpret_cast<const f16x8*>(&hbuf[p][kq][0]);
#pragma unroll
      for (int r8 = 0; r8 < 4; ++r8) {
        f16x8 h8 = hv8[r8];
        half2_t h0 = {h8[0], h8[1]}, h1 = {h8[2], h8[3]};
        half2_t h2 = {h8[4], h8[5]}, h3 = {h8[6], h8[7]};
        a0 = fdot2(wh[0][4 * r8 + 0], h0, a0); a0 = fdot2(wh[0][4 * r8 + 1], h1, a0);
        a0 = fdot2(wh[0][4 * r8 + 2], h2, a0); a0 = fdot2(wh[0][4 * r8 + 3], h3, a0);
        a1 = fdot2(wh[1][4 * r8 + 0], h0, a1); a1 = fdot2(wh[1][4 * r8 + 1], h1, a1);
        a1 = fdot2(wh[1][4 * r8 + 2], h2, a1); a1 = fdot2(wh[1][4 * r8 + 3], h3, a1);
        a2 = fdot2(wh[2][4 * r8 + 0], h0, a2); a2 = fdot2(wh[2][4 * r8 + 1], h1, a2);
        a2 = fdot2(wh[2][4 * r8 + 2], h2, a2); a2 = fdot2(wh[2][4 * r8 + 3], h3, a2);
        a3 = fdot2(wh[3][4 * r8 + 0], h0, a3); a3 = fdot2(wh[3][4 * r8 + 1], h1, a3);
        a3 = fdot2(wh[3][4 * r8 + 2], h2, a3); a3 = fdot2(wh[3][4 * r8 + 3], h3, a3);
      }
      a0 += __shfl_xor(a0, 1, 4); a0 += __shfl_xor(a0, 2, 4);
      a1 += __shfl_xor(a1, 1, 4); a1 += __shfl_xor(a1, 2, 4);
      a2 += __shfl_xor(a2, 1, 4); a2 += __shfl_xor(a2, 2, 4);
      a3 += __shfl_xor(a3, 1, 4); a3 += __shfl_xor(a3, 2, 4);

      float xi, xf, xgg, xo;
      if (MODE == 2) {
        xi = xgc[j]; xf = xgc[j + 128]; xgg = xgc[j + 256]; xo = xgc[j + 384];
      } else {
        const half_t* xb = &xgs[ch & 1][tt][0];
        xi = (float)xb[j]; xf = (float)xb[j + 128];
        xgg = (float)xb[j + 256]; xo = (float)xb[j + 384];
      }

      const float ig = sigm(a0 + xi);
      const float fg = sigm(a1 + xf);
      const float gg = tanh_(a2 + xgg);
      const float og = sigm(a3 + xo);
      c = fmaf(fg, c, ig * gg);
      const float h = og * tanh_(c);

      if (kq == 0) {
        hbuf[p ^ 1][j >> 5][j & 31] = (half_t)h;
        if (MODE != 1) seq_out[((size_t)b * NT + t) * NH + j] = (half_t)h;
        else if (t == NT - 1) hT_out[(size_t)b * NH + j] = h;
      }
      __syncthreads();
    }
  }
}

}  // namespace

extern "C" void kernel_launch(void* const* d_in, const int* in_sizes, int n_in,
                              void* d_out, int out_size, void* d_ws, size_t ws_size,
                              hipStream_t stream) {
  (void)in_sizes; (void)n_in; (void)out_size; (void)ws_size;

  const float* x     = (const float*)d_in[0];
  const float* e0Wih = (const float*)d_in[1];
  const float* e0Whh = (const float*)d_in[2];
  const float* e0bih = (const float*)d_in[3];
  const float* e0bhh = (const float*)d_in[4];
  const float* e1Wih = (const float*)d_in[5];
  const float* e1Whh = (const float*)d_in[6];
  const float* e1bih = (const float*)d_in[7];
  const float* e1bhh = (const float*)d_in[8];
  const float* d0Wih = (const float*)d_in[9];
  const float* d0Whh = (const float*)d_in[10];
  const float* d0bih = (const float*)d_in[11];
  const float* d0bhh = (const float*)d_in[12];
  const float* d1Wih = (const float*)d_in[13];
  const float* d1Whh = (const float*)d_in[14];
  const float* d1bih = (const float*)d_in[15];
  const float* d1bhh = (const float*)d_in[16];
  const float* Wout  = (const float*)d_in[17];
  const float* bout  = (const float*)d_in[18];
  float* out = (float*)d_out;

  // ---- workspace: Whh fp16 x4 | seqA fp16 [B*T,128] | xg fp16 [B*T,512] | hT f32 ----
  half_t* whh0 = (half_t*)d_ws;
  half_t* whh1 = whh0 + 512 * 128;
  half_t* whh2 = whh1 + 512 * 128;
  half_t* whh3 = whh2 + 512 * 128;
  half_t* seqA = whh3 + 512 * 128;                       // 16.8M halfs
  half_t* xgb  = seqA + (size_t)NB * NT * NH;            // 67.1M halfs
  float*  hT   = (float*)(xgb + (size_t)NB * NT * NG);   // 32K floats

  cvt_kernel<<<64, 256, 0, stream>>>(e0Whh, whh0, 512 * 128 / 4);
  cvt_kernel<<<64, 256, 0, stream>>>(e1Whh, whh1, 512 * 128 / 4);
  cvt_kernel<<<64, 256, 0, stream>>>(d0Whh, whh2, 512 * 128 / 4);
  cvt_kernel<<<64, 256, 0, stream>>>(d1Whh, whh3, 512 * 128 / 4);

  const int M = NB * NT;  // 131072
  dim3 gX(M / 128, NG / 64), gP(M / 128, 1), blkG(256);
  dim3 gR(NB), blkR(512);

  // enc0: xg0 = x @ e0Wih^T + b   (A fp32, K=64) -> rec -> seqA
  xg_gemm<64, true, false><<<gX, blkG, 0, stream>>>(x, e0Wih, e0bih, e0bhh, xgb, nullptr, NG);
  rec_kernel<0><<<gR, blkR, 0, stream>>>(xgb, nullptr, nullptr, nullptr, nullptr, whh0, seqA, nullptr);

  // enc1: xg1 = seqA @ e1Wih^T + b (A fp16, K=128) -> rec -> hT
  xg_gemm<128, false, false><<<gX, blkG, 0, stream>>>(seqA, e1Wih, e1bih, e1bhh, xgb, nullptr, NG);
  rec_kernel<1><<<gR, blkR, 0, stream>>>(xgb, nullptr, nullptr, nullptr, nullptr, whh1, nullptr, hT);

  // dec0: const xg from hT -> rec -> seqA
  rec_kernel<2><<<gR, blkR, 0, stream>>>(nullptr, hT, d0Wih, d0bih, d0bhh, whh2, seqA, nullptr);

  // dec1: xg3 = seqA @ d1Wih^T + b -> rec -> seqA (h-seq)
  xg_gemm<128, false, false><<<gX, blkG, 0, stream>>>(seqA, d1Wih, d1bih, d1bhh, xgb, nullptr, NG);
  rec_kernel<0><<<gR, blkR, 0, stream>>>(xgb, nullptr, nullptr, nullptr, nullptr, whh3, seqA, nullptr);

  // projection: out = seqA @ Wout^T + bout (fp32 out, N=64)
  xg_gemm<128, false, true><<<gP, blkG, 0, stream>>>(seqA, Wout, bout, nullptr, nullptr, out, 64);
}